// Round 11
// baseline (203.012 us; speedup 1.0000x reference)
//
#include <hip/hip_runtime.h>
#include <hip/hip_bf16.h>

// B=2, S=2048, D=1024, H=16, DK=64
// Pipeline (fp16 compute, fp32 accum):
//   1. prep: (a) x fp32->fp16, (b) W -> W^T fp16 (one fused kernel)
//   2. gemm_qkv: Q|K|V = x@W + b; Q pre-scaled by 1/sqrt(dk)*log2e;
//      V transposed via LDS in epilogue -> VT [B,H,DK,S]
//   3. attn: flash attention, S^T=K.Q^T operand swap, STATIC-MAX softmax
//      (linear partials => kv-splittable). Tiles qt>=16 split into two kv
//      halves; 1536 blocks of length 1..16 iters, single-buffered LDS
//      (18.4KB => 6 blocks/CU resident), 48-slot dispatch table makes every
//      CU residue sum to 66 iters. Split partials: h0 raw O -> ctx rows (f16),
//      h1 -> Ph1 scratch, denominators -> Lbuf.
//   4. combine: ctx = (O0+O1)/(l0+l1) for split rows (512 blocks)
//   5. gemm_out: out = ctx@Wo + bo -> fp32, 128x64 tiles (512 blocks)
// Workspace (40 MiB): xh@0 (later ctx), WTs@8M (dead after gemm_qkv ->
//   Ph1@8M 4MB, Lbuf@12M 256KB), WoT@14M, Qh@16M, Kh@24M, VT@32M.

typedef _Float16 f16x8 __attribute__((ext_vector_type(8)));
typedef _Float16 f16x4 __attribute__((ext_vector_type(4)));
typedef _Float16 f16x2 __attribute__((ext_vector_type(2)));
typedef float f32x4 __attribute__((ext_vector_type(4)));

#define QSCALE 0.180336880111112f /* 0.125 * log2(e) */

__device__ __forceinline__ void async_copy16(const _Float16* gsrc,
                                             _Float16* ldst) {
  __builtin_amdgcn_global_load_lds(
      (const __attribute__((address_space(1))) void*)gsrc,
      (__attribute__((address_space(3))) void*)ldst, 16, 0, 0);
}

// ---------------- prep: cvt_x (blocks 0..4095) + W^T (blocks 4096..8191) ----
__global__ __launch_bounds__(256) void prep(
    const float* __restrict__ x, _Float16* __restrict__ xh,
    const float* __restrict__ W0, const float* __restrict__ W1,
    const float* __restrict__ W2, const float* __restrict__ W3,
    _Float16* __restrict__ T0, _Float16* __restrict__ T1,
    _Float16* __restrict__ T2, _Float16* __restrict__ T3) {
  if (blockIdx.x < 4096) {
    int i = (blockIdx.x * 256 + threadIdx.x) * 4;
    float4 v = *(const float4*)(x + i);
    f16x4 o;
    o.x = (_Float16)v.x; o.y = (_Float16)v.y;
    o.z = (_Float16)v.z; o.w = (_Float16)v.w;
    *(f16x4*)(xh + i) = o;
    return;
  }
  const int id = blockIdx.x - 4096;
  const int w = id >> 10, rem = id & 1023;
  const int bx = rem & 31, by = rem >> 5;
  const float* W; _Float16* T;
  switch (w) {
    case 0: W = W0; T = T0; break;
    case 1: W = W1; T = T1; break;
    case 2: W = W2; T = T2; break;
    default: W = W3; T = T3; break;
  }
  __shared__ _Float16 tile[32][33];
  const int tx = threadIdx.x & 31, ty = threadIdx.x >> 5;
  const int n0 = bx * 32, k0 = by * 32;
  for (int i = 0; i < 4; i++) {
    int kk = k0 + ty + i * 8;
    tile[ty + i * 8][tx] = (_Float16)W[(size_t)kk * 1024 + n0 + tx];
  }
  __syncthreads();
  for (int i = 0; i < 4; i++) {
    int nn = n0 + ty + i * 8;
    T[(size_t)nn * 1024 + k0 + tx] = tile[tx][ty + i * 8];
  }
}

// ---------------- fused QKV GEMM ----------------
__global__ __launch_bounds__(256) void gemm_qkv(
    const _Float16* __restrict__ A, const _Float16* __restrict__ BtAll,
    const float* __restrict__ bq, const float* __restrict__ bk,
    const float* __restrict__ bv, _Float16* __restrict__ Qh,
    _Float16* __restrict__ Kh, _Float16* __restrict__ VT) {
  __shared__ _Float16 As[128 * 32];
  __shared__ _Float16 Bs[128 * 32];
  __shared__ _Float16 tbuf[64 * 136];  // V-transpose staging (epilogue only)
  const int tid = threadIdx.x;
  const int wave = tid >> 6, lane = tid & 63;
  const int lr = lane & 15, lq = lane >> 4;
  const int m0 = blockIdx.x * 128, n0 = blockIdx.y * 128;
  const int rw = (wave & 1) * 64, cw = (wave >> 1) * 64;

  const int sel = blockIdx.y >> 3;  // 0=Q 1=K 2=V
  const float* bias = sel == 0 ? bq : (sel == 1 ? bk : bv);
  const int c0 = n0 & 1023;

  f32x4 acc[4][4] = {};
  const int r0 = wave * 32 + (lane >> 2);
  const int woff = (lane & 3) * 8;

  for (int kt = 0; kt < 1024; kt += 32) {
    __syncthreads();
    async_copy16(A + (size_t)(m0 + r0) * 1024 + kt + woff, As + r0 * 32 + woff);
    async_copy16(A + (size_t)(m0 + r0 + 16) * 1024 + kt + woff,
                 As + (r0 + 16) * 32 + woff);
    async_copy16(BtAll + (size_t)(n0 + r0) * 1024 + kt + woff,
                 Bs + r0 * 32 + woff);
    async_copy16(BtAll + (size_t)(n0 + r0 + 16) * 1024 + kt + woff,
                 Bs + (r0 + 16) * 32 + woff);
    __syncthreads();
    f16x8 af[4], bf[4];
    for (int i = 0; i < 4; i++)
      af[i] = *(const f16x8*)(As + (rw + i * 16 + lr) * 32 + lq * 8);
    for (int j = 0; j < 4; j++)
      bf[j] = *(const f16x8*)(Bs + (cw + j * 16 + lr) * 32 + lq * 8);
    for (int i = 0; i < 4; i++)
      for (int j = 0; j < 4; j++)
        acc[i][j] = __builtin_amdgcn_mfma_f32_16x16x32_f16(af[i], bf[j],
                                                           acc[i][j], 0, 0, 0);
  }

  if (sel == 2) {
    // V: LDS-transpose epilogue -> VT [B,H,DK,S] with coalesced 256B stores.
    const int bb = m0 >> 11, ss0 = m0 & 2047;
    const int cs = tid & 15, dkr = tid >> 4;  // store assignment
    for (int jj = 0; jj < 2; jj++) {          // two 64-col halves (one head ea)
      __syncthreads();
      if ((wave >> 1) == jj) {  // waves owning cw == jj*64 write their acc
        for (int i = 0; i < 4; i++) {
          const int sl = rw + i * 16 + lq * 4;  // local row 0..127
          for (int j = 0; j < 4; j++) {
            const int dk = j * 16 + lr;  // local d within head
            const float bvl = bias[c0 + jj * 64 + dk];
            f16x4 pv;
            for (int r = 0; r < 4; r++) pv[r] = (_Float16)(acc[i][j][r] + bvl);
            *(f16x4*)(tbuf + dk * 136 + sl) = pv;
          }
        }
      }
      __syncthreads();
      const int hh = (c0 + jj * 64) >> 6;
      _Float16* dst = VT + ((size_t)(bb * 16 + hh) * 64) * 2048 + ss0;
      for (int k = 0; k < 4; k++) {
        const int dk = dkr + k * 16;
        *(uint4*)(dst + (size_t)dk * 2048 + cs * 8) =
            *(const uint4*)(tbuf + dk * 136 + cs * 8);
      }
    }
  } else {
    _Float16* out = sel == 0 ? Qh : Kh;
    const float scl = sel == 0 ? QSCALE : 1.0f;
    for (int i = 0; i < 4; i++) {
      const int row = m0 + rw + i * 16 + lq * 4;
      for (int j = 0; j < 4; j++) {
        const int col = c0 + cw + j * 16 + lr;
        const float bvl = bias[col];
        for (int r = 0; r < 4; r++)
          out[(size_t)(row + r) * 1024 + col] =
              (_Float16)((acc[i][j][r] + bvl) * scl);
      }
    }
  }
}

// ---------------- final GEMM: 128x64 tiles, 512 blocks ----------------
__global__ __launch_bounds__(256) void gemm_out(
    const _Float16* __restrict__ A, const _Float16* __restrict__ Bt,
    const float* __restrict__ bias, float* __restrict__ out) {
  __shared__ _Float16 As[128 * 32];
  __shared__ _Float16 Bs[64 * 32];
  const int tid = threadIdx.x;
  const int wave = tid >> 6, lane = tid & 63;
  const int lr = lane & 15, lq = lane >> 4;
  const int m0 = blockIdx.x * 128, n0 = blockIdx.y * 64;
  const int rw = (wave & 1) * 64, cw = (wave >> 1) * 32;
  f32x4 acc[4][2] = {};
  const int r0 = wave * 32 + (lane >> 2);
  const int br = tid >> 2;  // 0..63
  const int woff = (lane & 3) * 8;

  for (int kt = 0; kt < 1024; kt += 32) {
    __syncthreads();
    async_copy16(A + (size_t)(m0 + r0) * 1024 + kt + woff, As + r0 * 32 + woff);
    async_copy16(A + (size_t)(m0 + r0 + 16) * 1024 + kt + woff,
                 As + (r0 + 16) * 32 + woff);
    async_copy16(Bt + (size_t)(n0 + br) * 1024 + kt + woff,
                 Bs + br * 32 + woff);
    __syncthreads();
    f16x8 af[4], bf[2];
    for (int i = 0; i < 4; i++)
      af[i] = *(const f16x8*)(As + (rw + i * 16 + lr) * 32 + lq * 8);
    for (int j = 0; j < 2; j++)
      bf[j] = *(const f16x8*)(Bs + (cw + j * 16 + lr) * 32 + lq * 8);
    for (int i = 0; i < 4; i++)
      for (int j = 0; j < 2; j++)
        acc[i][j] = __builtin_amdgcn_mfma_f32_16x16x32_f16(af[i], bf[j],
                                                           acc[i][j], 0, 0, 0);
  }
  for (int i = 0; i < 4; i++) {
    const int row = m0 + rw + i * 16 + lq * 4;
    for (int j = 0; j < 2; j++) {
      const int col = n0 + cw + j * 16 + lr;
      const float bvl = bias[col];
      for (int r = 0; r < 4; r++)
        out[(size_t)(row + r) * 1024 + col] = acc[i][j][r] + bvl;
    }
  }
}

// ---------------- flash attention, kv-split ----------------
// grid (32 bh, 48 slot), 256 threads = 4 waves, single-buffered LDS (18.4KB,
// 6 blocks/CU). Slot table: qt>=16 tiles split into 2 kv halves; every CU
// residue's 6 blocks sum to exactly 66 iters, longest-first.
// STATIC-MAX softmax (no running max) => split partials combine linearly.
// h0 writes raw O (f16) into ctx's rows; h1 -> Ph1; denominators -> Lbuf.
__global__ __launch_bounds__(256) void attn(
    const _Float16* __restrict__ Q, const _Float16* __restrict__ K,
    const _Float16* __restrict__ VT, _Float16* __restrict__ ctx,
    _Float16* __restrict__ Ph1, float* __restrict__ Lbuf) {
#define E(q, lo, hi) ((q) | ((lo) << 8) | ((hi) << 16))
  static const unsigned int slots[48] = {
      E(31, 0, 16),  E(30, 0, 16),  E(29, 15, 30), E(14, 0, 15),
      E(13, 0, 14),  E(24, 0, 13),  E(23, 0, 12),  E(11, 0, 12),
      E(31, 16, 32), E(15, 0, 16),  E(28, 0, 15),  E(27, 14, 28),
      E(25, 0, 13),  E(12, 0, 13),  E(23, 12, 24), E(21, 0, 11),
      E(30, 16, 31), E(29, 0, 15),  E(28, 15, 29), E(26, 0, 14),
      E(25, 13, 26), E(24, 13, 25), E(22, 0, 12),  E(21, 11, 22),
      E(18, 10, 19), E(17, 9, 18),  E(27, 0, 14),  E(26, 14, 27),
      E(20, 11, 21), E(22, 12, 23), E(19, 0, 10),  E(20, 0, 11),
      E(17, 0, 9),   E(16, 9, 17),  E(4, 0, 5),    E(5, 0, 6),
      E(16, 0, 9),   E(8, 0, 9),    E(19, 10, 20), E(10, 0, 11),
      E(0, 0, 1),    E(1, 0, 2),    E(2, 0, 3),    E(3, 0, 4),
      E(6, 0, 7),    E(7, 0, 8),    E(9, 0, 10),   E(18, 0, 10)};
#undef E
  const unsigned int e = slots[blockIdx.y];
  const int qt = e & 63, kvlo = (e >> 8) & 63, kvhi = (e >> 16) & 63;
  const int bh = blockIdx.x;
  const int b = bh >> 4, h = bh & 15;
  const int tid = threadIdx.x, wave = tid >> 6, lane = tid & 63;
  const int lr = lane & 15, lq = lane >> 4;
  const int qmin = qt * 64 + wave * 16;  // wave's q rows (q = lr)
  const size_t qkbase = ((size_t)b * 2048) * 1024 + h * 64;
  const size_t vtbase = ((size_t)bh) * 64 * 2048;

  __shared__ _Float16 Ks[64 * 72];
  __shared__ _Float16 Vs[64 * 72];

  // Q fragments (pre-scaled by QSCALE in gemm_qkv)
  const _Float16* qp = Q + qkbase + (size_t)(qmin + lr) * 1024 + lq * 8;
  f16x8 qf0 = *(const f16x8*)qp;
  f16x8 qf1 = *(const f16x8*)(qp + 32);

  f16x4 onesf;  // B-operand col 0 = ones => D[:,0] = row sums of A
  {
    _Float16 ov = (lr == 0) ? (_Float16)1.0f : (_Float16)0.0f;
    for (int i = 0; i < 4; i++) onesf[i] = ov;
  }

  f32x4 o[4] = {};
  f32x4 ol = {};  // softmax denominator accumulator (col 0)

  const int sgr = tid >> 2, sgc = (tid & 3) * 8;
  const _Float16* Kg0 = K + qkbase + (size_t)sgr * 1024 + sgc;
  const _Float16* Vg0 = VT + vtbase + (size_t)sgr * 2048 + sgc;
  uint4 ka = *(const uint4*)(Kg0 + (size_t)kvlo * 64 * 1024);
  uint4 kb = *(const uint4*)(Kg0 + (size_t)kvlo * 64 * 1024 + 32);
  uint4 va = *(const uint4*)(Vg0 + kvlo * 64);
  uint4 vb = *(const uint4*)(Vg0 + kvlo * 64 + 32);

  for (int t = kvlo; t < kvhi; t++) {
    *(uint4*)(Ks + sgr * 72 + sgc) = ka;
    *(uint4*)(Ks + sgr * 72 + sgc + 32) = kb;
    *(uint4*)(Vs + sgr * 72 + sgc) = va;
    *(uint4*)(Vs + sgr * 72 + sgc + 32) = vb;
    __syncthreads();  // stores visible
    if (t + 1 < kvhi) {  // prefetch next tile; flies during compute
      const _Float16* kg = Kg0 + (size_t)(t + 1) * 64 * 1024;
      const _Float16* vg = Vg0 + (t + 1) * 64;
      ka = *(const uint4*)kg; kb = *(const uint4*)(kg + 32);
      va = *(const uint4*)vg; vb = *(const uint4*)(vg + 32);
    }

    const int kv0 = t * 64;
    // S^T = K.Q^T : s[ks][r] = S[q=lr][kv=kv0+ks*16+lq*4+r]
    f32x4 s[4];
    for (int ks = 0; ks < 4; ks++) {
      f16x8 k0 = *(const f16x8*)(Ks + (ks * 16 + lr) * 72 + lq * 8);
      f16x8 k1 = *(const f16x8*)(Ks + (ks * 16 + lr) * 72 + 32 + lq * 8);
      f32x4 z = {};
      z = __builtin_amdgcn_mfma_f32_16x16x32_f16(k0, qf0, z, 0, 0, 0);
      z = __builtin_amdgcn_mfma_f32_16x16x32_f16(k1, qf1, z, 0, 0, 0);
      s[ks] = z;
    }
    if (t == qt) {  // causal mask: diagonal tile only
      const int qcol = qmin + lr;
      for (int ks = 0; ks < 4; ks++)
        for (int r = 0; r < 4; r++)
          if (kv0 + ks * 16 + lq * 4 + r > qcol) s[ks][r] = -1e30f;
    }
    // static-max softmax: p = exp2(s)
    f16x4 pa[4];
    for (int ks = 0; ks < 4; ks++) {
      float p0 = exp2f(s[ks][0]);
      float p1 = exp2f(s[ks][1]);
      float p2 = exp2f(s[ks][2]);
      float p3 = exp2f(s[ks][3]);
      f16x2 q01 = __builtin_bit_cast(f16x2, __builtin_amdgcn_cvt_pkrtz(p0, p1));
      f16x2 q23 = __builtin_bit_cast(f16x2, __builtin_amdgcn_cvt_pkrtz(p2, p3));
      pa[ks] = __builtin_shufflevector(q01, q23, 0, 1, 2, 3);
    }
    // O += P.V ; denominator on the matrix pipe: ol += P.ones
    for (int ks = 0; ks < 4; ks++) {
      for (int dn = 0; dn < 4; dn++) {
        f16x4 vf = *(const f16x4*)(Vs + (dn * 16 + lr) * 72 + ks * 16 + lq * 4);
        o[dn] =
            __builtin_amdgcn_mfma_f32_16x16x16f16(pa[ks], vf, o[dn], 0, 0, 0);
      }
      ol = __builtin_amdgcn_mfma_f32_16x16x16f16(pa[ks], onesf, ol, 0, 0, 0);
    }
    __syncthreads();  // reads done; LDS reusable next iter
  }

  if (qt < 16) {
    // unsplit: normalize and store. D[q][0] at lane lq*16, reg r.
    for (int r = 0; r < 4; r++) {
      float lv = __shfl(ol[r], lane & 48);
      float inv = 1.0f / lv;
      const int row = qmin + lq * 4 + r;
      for (int dn = 0; dn < 4; dn++)
        ctx[qkbase + (size_t)row * 1024 + dn * 16 + lr] =
            (_Float16)(o[dn][r] * inv);
    }
  } else {
    // split: write raw partial O + denominator
    const int hh = kvlo ? 1 : 0;
    const int qtz = qt - 16;
    if (lr == 0) {  // lanes lq*16 hold D[lq*4+r][0]
      for (int r = 0; r < 4; r++)
        Lbuf[((hh * 32 + bh) * 16 + qtz) * 64 + wave * 16 + lq * 4 + r] = ol[r];
    }
    for (int r = 0; r < 4; r++) {
      const int lrow = wave * 16 + lq * 4 + r;  // 0..63
      if (hh == 0) {
        const int row = qmin + lq * 4 + r;
        for (int dn = 0; dn < 4; dn++)
          ctx[qkbase + (size_t)row * 1024 + dn * 16 + lr] =
              (_Float16)o[dn][r];
      } else {
        _Float16* pp = Ph1 + ((size_t)(bh * 16 + qtz) * 64 + lrow) * 64;
        for (int dn = 0; dn < 4; dn++)
          pp[dn * 16 + lr] = (_Float16)o[dn][r];
      }
    }
  }
}

// ---------------- combine split partials ----------------
// grid (16 qtz, 32 bh), 256 threads; ctx = (O0 + O1) / (l0 + l1), in place.
__global__ __launch_bounds__(256) void combine(_Float16* __restrict__ ctx,
                                               const _Float16* __restrict__ Ph1,
                                               const float* __restrict__ Lbuf) {
  const int qtz = blockIdx.x, bh = blockIdx.y;
  const int b = bh >> 4, hd = bh & 15;
  const int row = threadIdx.x >> 2, c0 = (threadIdx.x & 3) * 16;
  const float l0 = Lbuf[((0 * 32 + bh) * 16 + qtz) * 64 + row];
  const float l1 = Lbuf[((1 * 32 + bh) * 16 + qtz) * 64 + row];
  const float inv = 1.0f / (l0 + l1);
  const int s = (qtz + 16) * 64 + row;
  _Float16* cp = ctx + ((size_t)(b * 2048 + s)) * 1024 + hd * 64 + c0;
  const _Float16* pp = Ph1 + ((size_t)(bh * 16 + qtz) * 64 + row) * 64 + c0;
  for (int v = 0; v < 2; v++) {
    f16x8 a = *(const f16x8*)(cp + v * 8);
    f16x8 bb = *(const f16x8*)(pp + v * 8);
    f16x8 ov;
    for (int i = 0; i < 8; i++)
      ov[i] = (_Float16)(((float)a[i] + (float)bb[i]) * inv);
    *(f16x8*)(cp + v * 8) = ov;
  }
}

extern "C" void kernel_launch(void* const* d_in, const int* in_sizes, int n_in,
                              void* d_out, int out_size, void* d_ws,
                              size_t ws_size, hipStream_t stream) {
  const float* x  = (const float*)d_in[0];
  const float* Wq = (const float*)d_in[2];
  const float* bq = (const float*)d_in[3];
  const float* Wk = (const float*)d_in[4];
  const float* bk = (const float*)d_in[5];
  const float* Wv = (const float*)d_in[6];
  const float* bv = (const float*)d_in[7];
  const float* Wo = (const float*)d_in[8];
  const float* bo = (const float*)d_in[9];
  float* out = (float*)d_out;

  char* ws = (char*)d_ws;
  const size_t MB = 1 << 20;
  _Float16* xh  = (_Float16*)(ws);            // 8 MB; dead after gemm_qkv
  _Float16* WTs = (_Float16*)(ws + 8 * MB);   // WqT|WkT|WvT (dead after qkv)
  _Float16* WqT = WTs;
  _Float16* WkT = (_Float16*)(ws + 10 * MB);
  _Float16* WvT = (_Float16*)(ws + 12 * MB);
  _Float16* WoT = (_Float16*)(ws + 14 * MB);
  _Float16* Qh  = (_Float16*)(ws + 16 * MB);
  _Float16* Kh  = (_Float16*)(ws + 24 * MB);
  _Float16* VT  = (_Float16*)(ws + 32 * MB);  // [B,H,DK,S]
  _Float16* ctx = (_Float16*)(ws);            // over xh
  _Float16* Ph1 = (_Float16*)(ws + 8 * MB);   // over WqT/WkT (4 MB)
  float*    Lbf = (float*)(ws + 12 * MB);     // over WvT (256 KB)

  prep<<<8192, 256, 0, stream>>>(x, xh, Wq, Wk, Wv, Wo, WqT, WkT, WvT, WoT);
  gemm_qkv<<<dim3(32, 24), 256, 0, stream>>>(xh, WTs, bq, bk, bv, Qh, Kh, VT);
  attn<<<dim3(32, 48), 256, 0, stream>>>(Qh, Kh, VT, ctx, Ph1, Lbf);
  combine<<<dim3(16, 32), 256, 0, stream>>>(ctx, Ph1, Lbf);
  gemm_out<<<dim3(32, 16), 256, 0, stream>>>(ctx, WoT, bo, out);
}